// Round 6
// baseline (48.775 us; speedup 1.0000x reference)
//
#include <hip/hip_runtime.h>

// Spherical harmonics (lmax=3, normalize=True, component normalization)
// over edge vectors. pos: [N,3] f32; edge_index: [2,E] int; out: [E,16] f32.
//
// 4 edges per thread: all index loads + all 24 position gathers issued
// up-front (4x memory-level parallelism vs 1-edge-per-thread), then four
// {compute -> swizzled 16KB LDS tile -> coalesced nontemporal store} rounds.

#define SQ3f 1.7320508075688772f
#define SQ5f 2.2360679774997896f
#define SQ7f 2.6457513110645907f
#define C30f 0.9128709291752769f   // sqrt(5/6)
#define C32f 0.6123724356957945f   // sqrt(3/8)

typedef float f32x4 __attribute__((ext_vector_type(4)));

__global__ __launch_bounds__(256) void sh_edge_kernel(
    const float* __restrict__ pos,
    const int* __restrict__ eidx,
    f32x4* __restrict__ out4,
    int E)
{
    __shared__ float lds[256 * 16];   // 16 KB, reused for 4 sub-tiles

    const int t = threadIdx.x;
    const long long blk = blockIdx.x;
    const long long ebase = blk * 1024;
    const size_t total4 = (size_t)E * 4;

    // Phase 1: all index loads (coalesced), then all 24 gathers in flight.
    int se[4], de[4];
    #pragma unroll
    for (int j = 0; j < 4; ++j) {
        long long e = ebase + j * 256 + t;
        long long ec = (e < E) ? e : 0;      // clamped; result discarded later
        se[j] = eidx[ec];
        de[j] = eidx[E + ec];
    }

    float vx[4], vy[4], vz[4];
    #pragma unroll
    for (int j = 0; j < 4; ++j) {
        vx[j] = pos[3 * se[j] + 0] - pos[3 * de[j] + 0];
        vy[j] = pos[3 * se[j] + 1] - pos[3 * de[j] + 1];
        vz[j] = pos[3 * se[j] + 2] - pos[3 * de[j] + 2];
    }

    // Phase 2: four rounds of compute -> LDS transpose -> coalesced store.
    #pragma unroll
    for (int j = 0; j < 4; ++j) {
        long long e = ebase + j * 256 + t;
        if (e < E) {
            float r2 = vx[j] * vx[j] + vy[j] * vy[j] + vz[j] * vz[j];
            float r = sqrtf(r2);
            float inv = 1.0f / fmaxf(r, 1e-12f);   // matches reference max(r, EPS)

            float x = vx[j] * inv;
            float y = vy[j] * inv;
            float z = vz[j] * inv;

            float x2 = x * x;
            float y2 = y * y;
            float z2 = z * z;
            float x2z2 = x2 + z2;

            float s20 = SQ3f * x * z;
            float s21 = SQ3f * x * y;
            float s22 = y2 - 0.5f * x2z2;
            float s23 = SQ3f * y * z;
            float s24 = 0.5f * SQ3f * (z2 - x2);

            float fy2 = 4.0f * y2 - x2z2;

            float s30 = C30f * (s20 * z + s24 * x);
            float s31 = SQ5f * s20 * y;
            float s32 = C32f * fy2 * x;
            float s33 = 0.5f * y * (2.0f * y2 - 3.0f * x2z2);
            float s34 = C32f * z * fy2;
            float s35 = SQ5f * s24 * y;
            float s36 = C30f * (s24 * z - s20 * x);

            float4 val[4];
            val[0] = make_float4(1.0f,        SQ3f * x,   SQ3f * y,   SQ3f * z);
            val[1] = make_float4(SQ5f * s20,  SQ5f * s21, SQ5f * s22, SQ5f * s23);
            val[2] = make_float4(SQ5f * s24,  SQ7f * s30, SQ7f * s31, SQ7f * s32);
            val[3] = make_float4(SQ7f * s33,  SQ7f * s34, SQ7f * s35, SQ7f * s36);

            #pragma unroll
            for (int q = 0; q < 4; ++q) {
                int col = q ^ ((t >> 1) & 3);
                *reinterpret_cast<float4*>(&lds[t * 16 + 4 * col]) = val[q];
            }
        }

        __syncthreads();

        // Stream this sub-tile's 1024 float4s out, coalesced + nontemporal.
        const size_t base4 = (size_t)(ebase + j * 256) * 4;
        #pragma unroll
        for (int i = 0; i < 4; ++i) {
            int k = i * 256 + t;             // 0..1023 within the tile
            int r = k >> 2;                  // source LDS row
            int qq = k & 3;                  // float4 slot within that row
            int col = qq ^ ((r >> 1) & 3);   // undo swizzle
            f32x4 v = *reinterpret_cast<const f32x4*>(&lds[r * 16 + 4 * col]);
            size_t o = base4 + k;
            if (o < total4) {
                __builtin_nontemporal_store(v, &out4[o]);
            }
        }

        __syncthreads();   // LDS reused by next round
    }
}

extern "C" void kernel_launch(void* const* d_in, const int* in_sizes, int n_in,
                              void* d_out, int out_size, void* d_ws, size_t ws_size,
                              hipStream_t stream)
{
    const float* pos = (const float*)d_in[0];
    const int* eidx = (const int*)d_in[1];
    f32x4* out4 = (f32x4*)d_out;

    int E = in_sizes[1] / 2;
    int block = 256;
    int grid = (int)(((long long)E + 1023) / 1024);
    sh_edge_kernel<<<grid, block, 0, stream>>>(pos, eidx, out4, E);
}

// Round 7
// 46.048 us; speedup vs baseline: 1.0592x; 1.0592x over previous
//
#include <hip/hip_runtime.h>

// Spherical harmonics (lmax=3, normalize=True, component normalization)
// over edge vectors. pos: [N,3] f32; edge_index: [2,E] int; out: [E,16] f32.
//
// Round-5 structure (1 thread/edge, swizzled 16KB LDS transpose, coalesced
// nontemporal stores) + 2-deep software pipeline over grid-strided tiles:
// while storing tile k from LDS, tile k+1's index loads + pos gathers are
// already in flight, hiding the dependent gather chain under store issue.

#define SQ3f 1.7320508075688772f
#define SQ5f 2.2360679774997896f
#define SQ7f 2.6457513110645907f
#define C30f 0.9128709291752769f   // sqrt(5/6)
#define C32f 0.6123724356957945f   // sqrt(3/8)

typedef float f32x4 __attribute__((ext_vector_type(4)));

__device__ __forceinline__ void load_edge_vec(
    const float* __restrict__ pos, const int* __restrict__ eidx,
    long long tile, int t, int E,
    float& vx, float& vy, float& vz)
{
    long long e = tile * 256 + t;
    long long ec = (e < E) ? e : 0;          // clamped; result unused if OOB
    int s = eidx[ec];
    int d = eidx[E + ec];
    vx = pos[3 * s + 0] - pos[3 * d + 0];
    vy = pos[3 * s + 1] - pos[3 * d + 1];
    vz = pos[3 * s + 2] - pos[3 * d + 2];
}

__global__ __launch_bounds__(256) void sh_edge_kernel(
    const float* __restrict__ pos,
    const int* __restrict__ eidx,
    f32x4* __restrict__ out4,
    int E, int nTiles)
{
    __shared__ float lds[256 * 16];   // 16 KB

    const int t = threadIdx.x;
    const size_t total4 = (size_t)E * 4;

    long long tile = blockIdx.x;
    if (tile >= nTiles) return;

    float vx, vy, vz;
    load_edge_vec(pos, eidx, tile, t, E, vx, vy, vz);

    for (;;) {
        // ---- compute current tile -> swizzled LDS ----
        long long e = tile * 256 + t;
        if (e < E) {
            float r2 = vx * vx + vy * vy + vz * vz;
            float r = sqrtf(r2);
            float inv = 1.0f / fmaxf(r, 1e-12f);   // matches reference max(r, EPS)

            float x = vx * inv;
            float y = vy * inv;
            float z = vz * inv;

            float x2 = x * x;
            float y2 = y * y;
            float z2 = z * z;
            float x2z2 = x2 + z2;

            float s20 = SQ3f * x * z;
            float s21 = SQ3f * x * y;
            float s22 = y2 - 0.5f * x2z2;
            float s23 = SQ3f * y * z;
            float s24 = 0.5f * SQ3f * (z2 - x2);

            float fy2 = 4.0f * y2 - x2z2;

            float s30 = C30f * (s20 * z + s24 * x);
            float s31 = SQ5f * s20 * y;
            float s32 = C32f * fy2 * x;
            float s33 = 0.5f * y * (2.0f * y2 - 3.0f * x2z2);
            float s34 = C32f * z * fy2;
            float s35 = SQ5f * s24 * y;
            float s36 = C30f * (s24 * z - s20 * x);

            float4 val[4];
            val[0] = make_float4(1.0f,        SQ3f * x,   SQ3f * y,   SQ3f * z);
            val[1] = make_float4(SQ5f * s20,  SQ5f * s21, SQ5f * s22, SQ5f * s23);
            val[2] = make_float4(SQ5f * s24,  SQ7f * s30, SQ7f * s31, SQ7f * s32);
            val[3] = make_float4(SQ7f * s33,  SQ7f * s34, SQ7f * s35, SQ7f * s36);

            #pragma unroll
            for (int q = 0; q < 4; ++q) {
                int col = q ^ ((t >> 1) & 3);
                *reinterpret_cast<float4*>(&lds[t * 16 + 4 * col]) = val[q];
            }
        }

        // ---- issue next tile's loads (latency hidden under store phase) ----
        long long next = tile + gridDim.x;
        bool hasNext = (next < nTiles);
        float nvx, nvy, nvz;
        if (hasNext) {
            load_edge_vec(pos, eidx, next, t, E, nvx, nvy, nvz);
        }

        __syncthreads();

        // ---- stream current tile's 1024 float4s out, coalesced + NT ----
        const size_t base4 = (size_t)tile * 1024;
        #pragma unroll
        for (int i = 0; i < 4; ++i) {
            int k = i * 256 + t;             // 0..1023 within the tile
            int r = k >> 2;                  // source LDS row
            int qq = k & 3;                  // float4 slot within that row
            int col = qq ^ ((r >> 1) & 3);   // undo swizzle
            f32x4 v = *reinterpret_cast<const f32x4*>(&lds[r * 16 + 4 * col]);
            size_t o = base4 + k;
            if (o < total4) {
                __builtin_nontemporal_store(v, &out4[o]);
            }
        }

        if (!hasNext) break;
        __syncthreads();                     // LDS reused by next tile
        tile = next;
        vx = nvx; vy = nvy; vz = nvz;
    }
}

extern "C" void kernel_launch(void* const* d_in, const int* in_sizes, int n_in,
                              void* d_out, int out_size, void* d_ws, size_t ws_size,
                              hipStream_t stream)
{
    const float* pos = (const float*)d_in[0];
    const int* eidx = (const int*)d_in[1];
    f32x4* out4 = (f32x4*)d_out;

    int E = in_sizes[1] / 2;
    int nTiles = (int)(((long long)E + 255) / 256);
    int grid = nTiles < 2048 ? nTiles : 2048;
    sh_edge_kernel<<<grid, 256, 0, stream>>>(pos, eidx, out4, E, nTiles);
}

// Round 8
// 44.328 us; speedup vs baseline: 1.1003x; 1.0388x over previous
//
#include <hip/hip_runtime.h>

// Spherical harmonics (lmax=3, normalize=True, component normalization)
// over edge vectors. pos: [N,3] f32; edge_index: [2,E] int; out: [E,16] f32.
//
// ONE WAVE PER BLOCK (64 threads): no cross-wave barriers, so each wave's
// {index load -> random pos gather -> compute -> LDS transpose -> coalesced
// NT store} chain proceeds independently; resident waves on a CU interleave
// gather stalls with store bursts with zero synchronization coupling.
// LDS transpose keeps wave stores perfectly coalesced (64 x 16B = 1KB/instr).

#define SQ3f 1.7320508075688772f
#define SQ5f 2.2360679774997896f
#define SQ7f 2.6457513110645907f
#define C30f 0.9128709291752769f   // sqrt(5/6)
#define C32f 0.6123724356957945f   // sqrt(3/8)

typedef float f32x4 __attribute__((ext_vector_type(4)));

__global__ __launch_bounds__(64) void sh_edge_kernel(
    const float* __restrict__ pos,
    const int* __restrict__ eidx,
    f32x4* __restrict__ out4,
    int E)
{
    __shared__ float lds[64 * 16];   // 4 KB, one wave's tile

    const int t = threadIdx.x;       // 0..63
    const long long blk = blockIdx.x;
    const long long e = blk * 64 + t;

    if (e < E) {
        int s = eidx[e];       // sender (row 0)
        int d = eidx[E + e];   // receiver (row 1)

        float vx = pos[3 * s + 0] - pos[3 * d + 0];
        float vy = pos[3 * s + 1] - pos[3 * d + 1];
        float vz = pos[3 * s + 2] - pos[3 * d + 2];

        float r2 = vx * vx + vy * vy + vz * vz;
        float r = sqrtf(r2);
        float inv = 1.0f / fmaxf(r, 1e-12f);   // matches reference max(r, EPS)

        float x = vx * inv;
        float y = vy * inv;
        float z = vz * inv;

        float x2 = x * x;
        float y2 = y * y;
        float z2 = z * z;
        float x2z2 = x2 + z2;

        float s20 = SQ3f * x * z;
        float s21 = SQ3f * x * y;
        float s22 = y2 - 0.5f * x2z2;
        float s23 = SQ3f * y * z;
        float s24 = 0.5f * SQ3f * (z2 - x2);

        float fy2 = 4.0f * y2 - x2z2;

        float s30 = C30f * (s20 * z + s24 * x);
        float s31 = SQ5f * s20 * y;
        float s32 = C32f * fy2 * x;
        float s33 = 0.5f * y * (2.0f * y2 - 3.0f * x2z2);
        float s34 = C32f * z * fy2;
        float s35 = SQ5f * s24 * y;
        float s36 = C30f * (s24 * z - s20 * x);

        float4 val[4];
        val[0] = make_float4(1.0f,        SQ3f * x,   SQ3f * y,   SQ3f * z);
        val[1] = make_float4(SQ5f * s20,  SQ5f * s21, SQ5f * s22, SQ5f * s23);
        val[2] = make_float4(SQ5f * s24,  SQ7f * s30, SQ7f * s31, SQ7f * s32);
        val[3] = make_float4(SQ7f * s33,  SQ7f * s34, SQ7f * s35, SQ7f * s36);

        #pragma unroll
        for (int q = 0; q < 4; ++q) {
            int col = q ^ ((t >> 1) & 3);
            *reinterpret_cast<float4*>(&lds[t * 16 + 4 * col]) = val[q];
        }
    }

    __syncthreads();   // 1-wave block: compiles to a waitcnt, no real barrier

    // Stream the wave's 256 float4s out, coalesced + nontemporal.
    const size_t base4 = (size_t)blk * 256;
    const size_t total4 = (size_t)E * 4;
    #pragma unroll
    for (int i = 0; i < 4; ++i) {
        int k = i * 64 + t;              // 0..255 within the tile
        int r = k >> 2;                  // source LDS row (edge within block)
        int qq = k & 3;                  // float4 slot within that row
        int col = qq ^ ((r >> 1) & 3);   // undo swizzle
        f32x4 v = *reinterpret_cast<const f32x4*>(&lds[r * 16 + 4 * col]);
        size_t o = base4 + k;
        if (o < total4) {
            __builtin_nontemporal_store(v, &out4[o]);
        }
    }
}

extern "C" void kernel_launch(void* const* d_in, const int* in_sizes, int n_in,
                              void* d_out, int out_size, void* d_ws, size_t ws_size,
                              hipStream_t stream)
{
    const float* pos = (const float*)d_in[0];
    const int* eidx = (const int*)d_in[1];
    f32x4* out4 = (f32x4*)d_out;

    int E = in_sizes[1] / 2;
    int block = 64;
    int grid = (int)(((long long)E + 63) / 64);
    sh_edge_kernel<<<grid, block, 0, stream>>>(pos, eidx, out4, E);
}